// Round 1
// baseline (152.794 us; speedup 1.0000x reference)
//
#include <hip/hip_runtime.h>
#include <math.h>

#define TOPK 2048
#define NCLS 80      // reference: randint(0, 80)
#define NBIN 4096    // score-digest bins (uniform scores -> ~5/bin)
#define CMAX 2560    // candidate key capacity (K + tie-bin slack)
#define SMAX 20480   // LDS score-cache capacity (M = 20000 in reference)
#define K1B  32      // selection blocks (candidate partition by idx & 31)
#define STN  1024    // k_sel threads (16 waves)
#define PTN  1024    // k_prep threads
#define CTN  256     // k_cmp threads
#define CROWS 2      // k_cmp rows per block -> 1024 blocks (4 per CU)

struct SelP {
    const float* scores; const float* boxes; const int* classes;
    int M; int K;
    float4* sel_box; float* sel_score; int* sel_cls;
};

struct PreP {
    const int* sel_cls;
    int K;
    int* cstart;      // [NCLS+1] exclusive class starts
    short* clist;     // [K] row indices grouped by class
};

struct CmpP {
    const float4* sel_box; const float* sel_score; const int* sel_cls;
    const int* cstart; const short* clist;
    const float* sw1; const float* sb1; const float* sw2; const float* sb2;
    const float* sw3; const float* sb3;
    const float* lw1; const float* lb1; const float* lw2; const float* lb2;
    int K;
    float* out_boxes; float* out_scores; float* out_cls;
};

__device__ __forceinline__ float iou_of(float xi, float yi, float ai,
                                        float x2i, float y2i, float4 bj) {
    float ix1 = fmaxf(xi, bj.x), iy1 = fmaxf(yi, bj.y);
    float ix2 = fminf(x2i, bj.x + bj.z), iy2 = fminf(y2i, bj.y + bj.w);
    float iw = fmaxf(ix2 - ix1, 0.0f), ih = fmaxf(iy2 - iy1, 0.0f);
    float inter = iw * ih;
    float uni = ai + bj.z * bj.w - inter;
    return inter / (uni + 1e-6f);
}

// monotone non-decreasing digest; single quantization used in all passes
__device__ __forceinline__ int digest12(float s) {
    int v = (int)(s * 4096.0f);
    return v < 0 ? 0 : (v > NBIN - 1 ? NBIN - 1 : v);
}

__device__ __forceinline__ float key_score(unsigned long long kk) {
    unsigned mono = (unsigned)(kk >> 32);
    unsigned ob = (mono & 0x80000000u) ? (mono & 0x7FFFFFFFu) : ~mono;
    return __uint_as_float(ob);
}

// ---------------------------------------------------------------------------
// k_sel: 32 blocks redundantly find the exact top-K (jax.lax.top_k stable
// semantics) via binned counting-rank, entirely in LDS after ONE global
// score sweep. Suffix scan is shuffle-based (3 barriers, not 20). Each
// block gathers+writes only candidates whose ORIGINAL index satisfies
// (idx & 31) == bid -- deterministic disjoint partition.   [UNCHANGED]
// ---------------------------------------------------------------------------
__global__ __launch_bounds__(STN, 1) void k_sel(SelP p) {
    __shared__ float ssc[SMAX];                   // 80 KB score cache
    __shared__ int   bincur[NBIN];                // 16 KB count -> cursor
    __shared__ int   binbase[NBIN];               // 16 KB rank base
    __shared__ unsigned long long skeys[CMAX];    // 20 KB candidate keys
    __shared__ int   sfx[STN];                    // 4 KB inclusive suffix sums
    __shared__ int   wsum[STN / 64];              // wave-total suffix sums
    __shared__ int   sh_cT;

    int tid = threadIdx.x, bid = blockIdx.x;
    int M = p.M, K = p.K, M4 = M >> 2;

    for (int b = tid; b < NBIN; b += STN) bincur[b] = 0;
    __syncthreads();

    // ---- sweep 1 (the only full global pass): cache scores + histogram ----
    const float4* s4p = (const float4*)p.scores;
    for (int i4 = tid; i4 < M4; i4 += STN) {
        float4 v = s4p[i4];
        if (i4 < SMAX / 4) ((float4*)ssc)[i4] = v;
        atomicAdd(&bincur[digest12(v.x)], 1);
        atomicAdd(&bincur[digest12(v.y)], 1);
        atomicAdd(&bincur[digest12(v.z)], 1);
        atomicAdd(&bincur[digest12(v.w)], 1);
    }
    for (int i = M4 * 4 + tid; i < M; i += STN) {
        float s = p.scores[i];
        if (i < SMAX) ssc[i] = s;
        atomicAdd(&bincur[digest12(s)], 1);
    }
    __syncthreads();

    // ---- suffix scan (shuffle-based): sfx[t] = sum of chunk sums t.. ----
    {
        const int BPT = NBIN / STN;               // 4 bins per thread
        int c0 = tid * BPT, sum = 0;
        #pragma unroll
        for (int u = 0; u < BPT; u++) sum += bincur[c0 + u];
        int lane = tid & 63;
        int x = sum;
        #pragma unroll
        for (int off = 1; off < 64; off <<= 1) {  // in-wave inclusive suffix
            int v = __shfl_down(x, off, 64);
            if (lane + off < 64) x += v;
        }
        if (lane == 0) wsum[tid >> 6] = x;        // wave totals (16)
        __syncthreads();
        if (tid < STN / 64) {                     // suffix over wave totals
            int t = wsum[tid];
            #pragma unroll
            for (int off = 1; off < STN / 64; off <<= 1) {
                int v = __shfl_down(t, off, 64);
                if (tid + off < STN / 64) t += v;
            }
            wsum[tid] = t;
        }
        __syncthreads();
        int wid = tid >> 6;
        int higher = (wid < STN / 64 - 1) ? wsum[wid + 1] : 0;
        sfx[tid] = x + higher;                    // global inclusive suffix
    }
    __syncthreads();

    // ---- binbase per bin + find crossing bin cT ----
    {
        const int BPT = NBIN / STN;
        int running = (tid < STN - 1) ? sfx[tid + 1] : 0;
        int c0 = tid * BPT;
        for (int u = BPT - 1; u >= 0; u--) {
            int b = c0 + u, cnt = bincur[b];
            binbase[b] = running;
            if (running < K && running + cnt >= K) sh_cT = b;  // unique bin
            running += cnt;
        }
    }
    __syncthreads();
    int cT = sh_cT;
    for (int b = tid; b < NBIN; b += STN) bincur[b] = binbase[b];
    __syncthreads();

    // ---- sweep 2 (from LDS): scatter candidate keys into bin slots ----
    // key = monotonic(score bits) << 32 | (0xFFFFFFFF - i): descending key ==
    // descending score, ties -> lower index (stable top_k semantics).
    for (int i = tid; i < M; i += STN) {
        float s = (i < SMAX) ? ssc[i] : p.scores[i];
        int d = digest12(s);
        if (d >= cT) {
            int slot = atomicAdd(&bincur[d], 1);
            if (slot < CMAX) {
                unsigned b = __float_as_uint(s);
                b = (b & 0x80000000u) ? ~b : (b | 0x80000000u);
                skeys[slot] = ((unsigned long long)b << 32) |
                              (unsigned long long)(0xFFFFFFFFu - (unsigned)i);
            }
        }
    }
    __syncthreads();

    // ---- exact rank within bin (~5 peers) + gather/write own partition ----
    {
        int C = bincur[cT]; if (C > CMAX) C = CMAX;
        const float4* boxes4 = (const float4*)p.boxes;
        for (int s = tid; s < C; s += STN) {
            unsigned long long ks = skeys[s];
            unsigned idx = 0xFFFFFFFFu - (unsigned)(ks & 0xFFFFFFFFull);
            if ((int)(idx & (K1B - 1)) != bid) continue;   // partition by index
            float sc = key_score(ks);
            int d = digest12(sc);
            int st = binbase[d], en = bincur[d]; if (en > CMAX) en = CMAX;
            int r = binbase[d];
            for (int t = st; t < en; t++) r += (skeys[t] > ks) ? 1 : 0;
            if (r < K) {
                p.sel_box[r] = boxes4[idx];
                p.sel_score[r] = sc;
                p.sel_cls[r] = p.classes[idx];
            }
        }
    }
}

// ---------------------------------------------------------------------------
// k_prep: ONE block builds the per-class lists ONCE (previously rebuilt
// redundantly by every k_cmp block: 2048 hist atomics + O(80) serial prefix
// + 2048 scatter atomics x 256 blocks). Wave-shuffle scan over the 80 bins.
// ---------------------------------------------------------------------------
__global__ __launch_bounds__(PTN, 1) void k_prep(PreP p) {
    __shared__ int ccnt[NCLS];
    __shared__ int ccur[NCLS];
    __shared__ int wtot;

    int tid = threadIdx.x;
    int K = p.K;
    if (tid < NCLS) ccnt[tid] = 0;
    __syncthreads();

    for (int r = tid; r < K; r += PTN) atomicAdd(&ccnt[p.sel_cls[r]], 1);
    __syncthreads();

    // exclusive scan of 80 counts: inclusive wave scan (waves 0,1) + carry
    int x = 0, v = 0;
    if (tid < 128) {
        v = (tid < NCLS) ? ccnt[tid] : 0;
        x = v;
        #pragma unroll
        for (int off = 1; off < 64; off <<= 1) {
            int t = __shfl_up(x, off, 64);
            if ((tid & 63) >= off) x += t;
        }
        if (tid == 63) wtot = x;                  // total of classes 0..63
    }
    __syncthreads();
    if (tid < NCLS) {
        int excl = x - v + ((tid >= 64) ? wtot : 0);
        ccur[tid] = excl;
        p.cstart[tid] = excl;
    }
    if (tid == 0) p.cstart[NCLS] = K;
    __syncthreads();

    // scatter rows grouped by class (order within class irrelevant: sums)
    for (int r = tid; r < K; r += PTN) {
        int pos = atomicAdd(&ccur[p.sel_cls[r]], 1);
        p.clist[pos] = (short)r;
    }
}

// ---------------------------------------------------------------------------
// k_cmp: 1024 blocks x 2 rows, 4 blocks/CU (16 waves/CU target). No LDS
// staging of the 56 KB sel arrays -- they are L2-resident and read directly
// (Common-mistake #7). LDS = MLP weights only (3.7 KB). MLP fused (no h[32])
// to fit 128 VGPR; identical FP accumulation order to previous kernel.
// ---------------------------------------------------------------------------
__global__ __launch_bounds__(CTN, 4) void k_cmp(CmpP p) {
    __shared__ float swt[914];                    // sup MLP 801 + lambda 113
    __shared__ float wpart[4];                    // per-wave D partials
    __shared__ int   rowc[CROWS];                 // class start per row
    __shared__ int   prefix[CROWS + 1];
    __shared__ float Ssum[CROWS], Drow[CROWS];

    int tid = threadIdx.x, bid = blockIdx.x;
    int K = p.K;
    int r0 = bid * CROWS;
    int nrows = K - r0; if (nrows > CROWS) nrows = CROWS;
    if (nrows <= 0) return;

    // ---- stage MLP weights (only LDS staging left) ----
    for (int t = tid; t < 224; t += CTN) swt[t] = p.sw1[t];
    if (tid < 32) swt[224 + tid] = p.sb1[tid];
    for (int t = tid; t < 512; t += CTN) swt[256 + t] = p.sw2[t];
    if (tid < 16) swt[768 + tid] = p.sb2[tid];
    if (tid < 16) swt[784 + tid] = p.sw3[tid];
    if (tid == 0) swt[800] = p.sb3[0];
    if (tid < 80) swt[801 + tid] = p.lw1[tid];
    if (tid < 16) swt[881 + tid] = p.lb1[tid];
    if (tid < 16) swt[897 + tid] = p.lw2[tid];
    if (tid == 0) swt[913] = p.lb2[0];

    // ---- per-row class range from precomputed cstart ----
    if (tid < CROWS) {
        Ssum[tid] = 0.0f;
        int st = 0, cnt = 0;
        if (tid < nrows) {
            int c = p.sel_cls[r0 + tid];
            st = p.cstart[c];
            cnt = p.cstart[c + 1] - st;
        }
        rowc[tid] = st;
        prefix[tid] = cnt;                        // temp: counts
    }
    __syncthreads();
    if (tid == 0) {                               // 2-element prefix
        int a0 = prefix[0], a1 = prefix[1];
        prefix[0] = 0; prefix[1] = a0; prefix[2] = a0 + a1;
    }

    // ---- Phase A: D row means; 2 waves per row, boxes straight from L2 ----
    {
        int wv = tid >> 6, lane = tid & 63;
        int row = wv >> 1, half = wv & 1;
        float dsum = 0.0f;
        if (row < nrows) {
            float4 bi = p.sel_box[r0 + row];
            float ai = bi.z * bi.w, x2i = bi.x + bi.z, y2i = bi.y + bi.w;
            for (int j = lane + (half << 6); j < K; j += 128)
                dsum += iou_of(bi.x, bi.y, ai, x2i, y2i, p.sel_box[j]);
            #pragma unroll
            for (int off = 32; off >= 1; off >>= 1)
                dsum += __shfl_xor(dsum, off, 64);
        }
        if (lane == 0) wpart[wv] = dsum;
    }
    __syncthreads();
    if (tid < nrows) Drow[tid] = (wpart[2 * tid] + wpart[2 * tid + 1]) / (float)K;

    int Pb = prefix[CROWS];
    const float* W1 = swt;       const float* B1 = swt + 224;
    const float* W2 = swt + 256; const float* B2 = swt + 768;
    const float* W3 = swt + 784; float B3 = swt[800];

    // ---- Phase B: flat per-pair fused MLP (j from precomputed clist) ----
    for (int pp = tid; pp < Pb; pp += CTN) {
        int row = (pp >= prefix[1]) ? 1 : 0;
        int j = (int)p.clist[rowc[row] + (pp - prefix[row])];
        float4 bi = p.sel_box[r0 + row];
        float4 bj = p.sel_box[j];
        float ai = bi.z * bi.w, x2i = bi.x + bi.z, y2i = bi.y + bi.w;
        float iou = iou_of(bi.x, bi.y, ai, x2i, y2i, bj);
        float f1 = fabsf(bi.x - bj.x), f2 = fabsf(bi.y - bj.y);
        float f3 = fabsf(bi.z - bj.z), f4 = fabsf(bi.w - bj.w);
        float f5 = p.sel_score[r0 + row], f6 = p.sel_score[j];
        float acc2[16];
        #pragma unroll
        for (int q = 0; q < 16; q++) acc2[q] = B2[q];
        #pragma unroll
        for (int o = 0; o < 32; o++) {
            float a = B1[o];
            a += iou * W1[0 * 32 + o];
            a += f1 * W1[1 * 32 + o];
            a += f2 * W1[2 * 32 + o];
            a += f3 * W1[3 * 32 + o];
            a += f4 * W1[4 * 32 + o];
            a += f5 * W1[5 * 32 + o];
            a += f6 * W1[6 * 32 + o];
            float h = fmaxf(a, 0.0f);
            #pragma unroll
            for (int q = 0; q < 16; q++) acc2[q] += h * W2[o * 16 + q];
        }
        float acc3 = B3;
        #pragma unroll
        for (int q = 0; q < 16; q++) acc3 += fmaxf(acc2[q], 0.0f) * W3[q];
        atomicAdd(&Ssum[row], iou / (1.0f + expf(-acc3)));
    }
    __syncthreads();

    // ---- finale: lambda MLP + outputs for this block's rows ----
    if (tid < nrows) {
        int r = r0 + tid;
        float4 bi = p.sel_box[r];
        float si = p.sel_score[r];
        const float* LW1 = swt + 801; const float* LB1 = swt + 881;
        const float* LW2 = swt + 897; float LB2 = swt[913];
        float in5[5] = { bi.x, bi.y, bi.z, bi.w, si };
        float acc = LB2;
        #pragma unroll
        for (int o = 0; o < 16; o++) {
            float a2 = LB1[o];
            #pragma unroll
            for (int f = 0; f < 5; f++) a2 += in5[f] * LW1[f * 16 + o];
            acc += fmaxf(a2, 0.0f) * LW2[o];
        }
        float lam = 1.0f / (1.0f + expf(-acc));
        ((float4*)p.out_boxes)[r] = bi;
        p.out_cls[r] = (float)p.sel_cls[r];
        p.out_scores[r] = si * expf(-lam * Ssum[tid] * Drow[tid]);
    }
}

extern "C" void kernel_launch(void* const* d_in, const int* in_sizes, int n_in,
                              void* d_out, int out_size, void* d_ws, size_t ws_size,
                              hipStream_t stream) {
    int M = in_sizes[1];
    int K = (M < TOPK) ? M : TOPK;

    char* ws = (char*)d_ws;
    float4* sel_box   = (float4*)ws;           ws += (size_t)TOPK * 16;
    float*  sel_score = (float*)ws;            ws += (size_t)TOPK * 4;
    int*    sel_cls   = (int*)ws;              ws += (size_t)TOPK * 4;
    int*    cstart    = (int*)ws;              ws += (size_t)(NCLS + 2) * 4;
    short*  clist     = (short*)ws;            ws += (size_t)TOPK * 2;

    SelP sp;
    sp.scores  = (const float*)d_in[1];
    sp.boxes   = (const float*)d_in[0];
    sp.classes = (const int*)d_in[2];
    sp.M = M; sp.K = K;
    sp.sel_box = sel_box; sp.sel_score = sel_score; sp.sel_cls = sel_cls;

    PreP pp;
    pp.sel_cls = sel_cls; pp.K = K;
    pp.cstart = cstart; pp.clist = clist;

    CmpP cp;
    cp.sel_box = sel_box; cp.sel_score = sel_score; cp.sel_cls = sel_cls;
    cp.cstart = cstart; cp.clist = clist;
    cp.sw1 = (const float*)d_in[3];  cp.sb1 = (const float*)d_in[4];
    cp.sw2 = (const float*)d_in[5];  cp.sb2 = (const float*)d_in[6];
    cp.sw3 = (const float*)d_in[7];  cp.sb3 = (const float*)d_in[8];
    cp.lw1 = (const float*)d_in[9];  cp.lb1 = (const float*)d_in[10];
    cp.lw2 = (const float*)d_in[11]; cp.lb2 = (const float*)d_in[12];
    cp.K = K;
    cp.out_boxes  = (float*)d_out;
    cp.out_scores = (float*)d_out + (size_t)K * 4;
    cp.out_cls    = (float*)d_out + (size_t)K * 5;

    k_sel<<<K1B, STN, 0, stream>>>(sp);
    k_prep<<<1, PTN, 0, stream>>>(pp);
    k_cmp<<<(K + CROWS - 1) / CROWS, CTN, 0, stream>>>(cp);
}

// Round 2
// 106.450 us; speedup vs baseline: 1.4354x; 1.4354x over previous
//
#include <hip/hip_runtime.h>
#include <math.h>

#define TOPK 2048
#define NCLS 80      // reference: randint(0, 80)
#define NBIN 4096    // score-digest bins (uniform scores -> ~5/bin)
#define CMAX 2560    // candidate key capacity (K + tie-bin slack)
#define SMAX 20480   // LDS score-cache capacity (M = 20000 in reference)
#define K1B  32      // selection blocks (candidate partition by idx & 31)
#define STN  1024    // k_sel threads (16 waves)
#define PTN  1024    // k_prep threads
#define CTN  256     // k_cmp threads
#define CROWS 2      // k_cmp rows per block -> 1024 blocks

struct SelP {
    const float* scores; const float* boxes; const int* classes;
    int M; int K;
    float4* sel_box; float* sel_score; int* sel_cls;
};

struct PreP {
    const int* sel_cls;
    int K;
    int* cstart;      // [NCLS+1] exclusive class starts
    short* clist;     // [K] row indices grouped by class
};

struct CmpP {
    const float4* sel_box; const float* sel_score; const int* sel_cls;
    const int* cstart; const short* clist;
    const float* sw1; const float* sb1; const float* sw2; const float* sb2;
    const float* sw3; const float* sb3;
    const float* lw1; const float* lb1; const float* lw2; const float* lb2;
    int K;
    float* out_boxes; float* out_scores; float* out_cls;
};

__device__ __forceinline__ float iou_of(float xi, float yi, float ai,
                                        float x2i, float y2i, float4 bj) {
    float ix1 = fmaxf(xi, bj.x), iy1 = fmaxf(yi, bj.y);
    float ix2 = fminf(x2i, bj.x + bj.z), iy2 = fminf(y2i, bj.y + bj.w);
    float iw = fmaxf(ix2 - ix1, 0.0f), ih = fmaxf(iy2 - iy1, 0.0f);
    float inter = iw * ih;
    float uni = ai + bj.z * bj.w - inter;
    return inter / (uni + 1e-6f);
}

// monotone non-decreasing digest; single quantization used in all passes
__device__ __forceinline__ int digest12(float s) {
    int v = (int)(s * 4096.0f);
    return v < 0 ? 0 : (v > NBIN - 1 ? NBIN - 1 : v);
}

__device__ __forceinline__ float key_score(unsigned long long kk) {
    unsigned mono = (unsigned)(kk >> 32);
    unsigned ob = (mono & 0x80000000u) ? (mono & 0x7FFFFFFFu) : ~mono;
    return __uint_as_float(ob);
}

// ---------------------------------------------------------------------------
// k_sel: 32 blocks redundantly find the exact top-K (jax.lax.top_k stable
// semantics) via binned counting-rank, entirely in LDS after ONE global
// score sweep. Suffix scan is shuffle-based (3 barriers, not 20). Each
// block gathers+writes only candidates whose ORIGINAL index satisfies
// (idx & 31) == bid -- deterministic disjoint partition.   [UNCHANGED]
// ---------------------------------------------------------------------------
__global__ __launch_bounds__(STN, 1) void k_sel(SelP p) {
    __shared__ float ssc[SMAX];                   // 80 KB score cache
    __shared__ int   bincur[NBIN];                // 16 KB count -> cursor
    __shared__ int   binbase[NBIN];               // 16 KB rank base
    __shared__ unsigned long long skeys[CMAX];    // 20 KB candidate keys
    __shared__ int   sfx[STN];                    // 4 KB inclusive suffix sums
    __shared__ int   wsum[STN / 64];              // wave-total suffix sums
    __shared__ int   sh_cT;

    int tid = threadIdx.x, bid = blockIdx.x;
    int M = p.M, K = p.K, M4 = M >> 2;

    for (int b = tid; b < NBIN; b += STN) bincur[b] = 0;
    __syncthreads();

    // ---- sweep 1 (the only full global pass): cache scores + histogram ----
    const float4* s4p = (const float4*)p.scores;
    for (int i4 = tid; i4 < M4; i4 += STN) {
        float4 v = s4p[i4];
        if (i4 < SMAX / 4) ((float4*)ssc)[i4] = v;
        atomicAdd(&bincur[digest12(v.x)], 1);
        atomicAdd(&bincur[digest12(v.y)], 1);
        atomicAdd(&bincur[digest12(v.z)], 1);
        atomicAdd(&bincur[digest12(v.w)], 1);
    }
    for (int i = M4 * 4 + tid; i < M; i += STN) {
        float s = p.scores[i];
        if (i < SMAX) ssc[i] = s;
        atomicAdd(&bincur[digest12(s)], 1);
    }
    __syncthreads();

    // ---- suffix scan (shuffle-based): sfx[t] = sum of chunk sums t.. ----
    {
        const int BPT = NBIN / STN;               // 4 bins per thread
        int c0 = tid * BPT, sum = 0;
        #pragma unroll
        for (int u = 0; u < BPT; u++) sum += bincur[c0 + u];
        int lane = tid & 63;
        int x = sum;
        #pragma unroll
        for (int off = 1; off < 64; off <<= 1) {  // in-wave inclusive suffix
            int v = __shfl_down(x, off, 64);
            if (lane + off < 64) x += v;
        }
        if (lane == 0) wsum[tid >> 6] = x;        // wave totals (16)
        __syncthreads();
        if (tid < STN / 64) {                     // suffix over wave totals
            int t = wsum[tid];
            #pragma unroll
            for (int off = 1; off < STN / 64; off <<= 1) {
                int v = __shfl_down(t, off, 64);
                if (tid + off < STN / 64) t += v;
            }
            wsum[tid] = t;
        }
        __syncthreads();
        int wid = tid >> 6;
        int higher = (wid < STN / 64 - 1) ? wsum[wid + 1] : 0;
        sfx[tid] = x + higher;                    // global inclusive suffix
    }
    __syncthreads();

    // ---- binbase per bin + find crossing bin cT ----
    {
        const int BPT = NBIN / STN;
        int running = (tid < STN - 1) ? sfx[tid + 1] : 0;
        int c0 = tid * BPT;
        for (int u = BPT - 1; u >= 0; u--) {
            int b = c0 + u, cnt = bincur[b];
            binbase[b] = running;
            if (running < K && running + cnt >= K) sh_cT = b;  // unique bin
            running += cnt;
        }
    }
    __syncthreads();
    int cT = sh_cT;
    for (int b = tid; b < NBIN; b += STN) bincur[b] = binbase[b];
    __syncthreads();

    // ---- sweep 2 (from LDS): scatter candidate keys into bin slots ----
    // key = monotonic(score bits) << 32 | (0xFFFFFFFF - i): descending key ==
    // descending score, ties -> lower index (stable top_k semantics).
    for (int i = tid; i < M; i += STN) {
        float s = (i < SMAX) ? ssc[i] : p.scores[i];
        int d = digest12(s);
        if (d >= cT) {
            int slot = atomicAdd(&bincur[d], 1);
            if (slot < CMAX) {
                unsigned b = __float_as_uint(s);
                b = (b & 0x80000000u) ? ~b : (b | 0x80000000u);
                skeys[slot] = ((unsigned long long)b << 32) |
                              (unsigned long long)(0xFFFFFFFFu - (unsigned)i);
            }
        }
    }
    __syncthreads();

    // ---- exact rank within bin (~5 peers) + gather/write own partition ----
    {
        int C = bincur[cT]; if (C > CMAX) C = CMAX;
        const float4* boxes4 = (const float4*)p.boxes;
        for (int s = tid; s < C; s += STN) {
            unsigned long long ks = skeys[s];
            unsigned idx = 0xFFFFFFFFu - (unsigned)(ks & 0xFFFFFFFFull);
            if ((int)(idx & (K1B - 1)) != bid) continue;   // partition by index
            float sc = key_score(ks);
            int d = digest12(sc);
            int st = binbase[d], en = bincur[d]; if (en > CMAX) en = CMAX;
            int r = binbase[d];
            for (int t = st; t < en; t++) r += (skeys[t] > ks) ? 1 : 0;
            if (r < K) {
                p.sel_box[r] = boxes4[idx];
                p.sel_score[r] = sc;
                p.sel_cls[r] = p.classes[idx];
            }
        }
    }
}

// ---------------------------------------------------------------------------
// k_prep: ONE block builds the per-class lists ONCE. Wave-shuffle scan over
// the 80 class bins.   [UNCHANGED]
// ---------------------------------------------------------------------------
__global__ __launch_bounds__(PTN, 1) void k_prep(PreP p) {
    __shared__ int ccnt[NCLS];
    __shared__ int ccur[NCLS];
    __shared__ int wtot;

    int tid = threadIdx.x;
    int K = p.K;
    if (tid < NCLS) ccnt[tid] = 0;
    __syncthreads();

    for (int r = tid; r < K; r += PTN) atomicAdd(&ccnt[p.sel_cls[r]], 1);
    __syncthreads();

    // exclusive scan of 80 counts: inclusive wave scan (waves 0,1) + carry
    int x = 0, v = 0;
    if (tid < 128) {
        v = (tid < NCLS) ? ccnt[tid] : 0;
        x = v;
        #pragma unroll
        for (int off = 1; off < 64; off <<= 1) {
            int t = __shfl_up(x, off, 64);
            if ((tid & 63) >= off) x += t;
        }
        if (tid == 63) wtot = x;                  // total of classes 0..63
    }
    __syncthreads();
    if (tid < NCLS) {
        int excl = x - v + ((tid >= 64) ? wtot : 0);
        ccur[tid] = excl;
        p.cstart[tid] = excl;
    }
    if (tid == 0) p.cstart[NCLS] = K;
    __syncthreads();

    // scatter rows grouped by class (order within class irrelevant: sums)
    for (int r = tid; r < K; r += PTN) {
        int pos = atomicAdd(&ccur[p.sel_cls[r]], 1);
        p.clist[pos] = (short)r;
    }
}

// ---------------------------------------------------------------------------
// k_cmp: 1024 blocks x 2 rows. SPILL FIX vs round 1:
//  - __launch_bounds__(CTN, 2): 128-reg cap (round 1's (CTN,4) forced a
//    64-reg cap -> 57 MB/dispatch of scratch spill = the whole regression).
//  - MLP o-loop `#pragma unroll 2`: caps in-flight LDS weight loads at
//    2x(7+16) instead of 512, so demand (~85 regs) stays under the cap.
//  - Phase A loads each bj ONCE and accumulates vs both rows: halves L2
//    read traffic (67 -> 33.5 MB), same FLOPs.
// Sel arrays read straight from L2 (proven L2-resident in round 0).
// ---------------------------------------------------------------------------
__global__ __launch_bounds__(CTN, 2) void k_cmp(CmpP p) {
    __shared__ float swt[914];                    // sup MLP 801 + lambda 113
    __shared__ float wpart[8];                    // [wave][row] D partials
    __shared__ int   rowc[CROWS];                 // class start per row
    __shared__ int   prefix[CROWS + 1];
    __shared__ float Ssum[CROWS], Drow[CROWS];

    int tid = threadIdx.x, bid = blockIdx.x;
    int K = p.K;
    int r0 = bid * CROWS;
    int nrows = K - r0; if (nrows > CROWS) nrows = CROWS;
    if (nrows <= 0) return;

    // ---- stage MLP weights (only LDS staging) ----
    for (int t = tid; t < 224; t += CTN) swt[t] = p.sw1[t];
    if (tid < 32) swt[224 + tid] = p.sb1[tid];
    for (int t = tid; t < 512; t += CTN) swt[256 + t] = p.sw2[t];
    if (tid < 16) swt[768 + tid] = p.sb2[tid];
    if (tid < 16) swt[784 + tid] = p.sw3[tid];
    if (tid == 0) swt[800] = p.sb3[0];
    if (tid < 80) swt[801 + tid] = p.lw1[tid];
    if (tid < 16) swt[881 + tid] = p.lb1[tid];
    if (tid < 16) swt[897 + tid] = p.lw2[tid];
    if (tid == 0) swt[913] = p.lb2[0];

    // ---- per-row class range from precomputed cstart ----
    if (tid < CROWS) {
        Ssum[tid] = 0.0f;
        int st = 0, cnt = 0;
        if (tid < nrows) {
            int c = p.sel_cls[r0 + tid];
            st = p.cstart[c];
            cnt = p.cstart[c + 1] - st;
        }
        rowc[tid] = st;
        prefix[tid] = cnt;                        // temp: counts
    }
    __syncthreads();
    if (tid == 0) {                               // 2-element prefix
        int a0 = prefix[0], a1 = prefix[1];
        prefix[0] = 0; prefix[1] = a0; prefix[2] = a0 + a1;
    }

    // ---- Phase A: D row means; each thread loads bj once, feeds BOTH rows ----
    {
        float4 bi0 = p.sel_box[r0];
        float4 bi1 = (nrows > 1) ? p.sel_box[r0 + 1] : bi0;
        float a0 = bi0.z * bi0.w, x20 = bi0.x + bi0.z, y20 = bi0.y + bi0.w;
        float a1 = bi1.z * bi1.w, x21 = bi1.x + bi1.z, y21 = bi1.y + bi1.w;
        float d0 = 0.0f, d1 = 0.0f;
        for (int j = tid; j < K; j += CTN) {
            float4 bj = p.sel_box[j];
            d0 += iou_of(bi0.x, bi0.y, a0, x20, y20, bj);
            d1 += iou_of(bi1.x, bi1.y, a1, x21, y21, bj);
        }
        #pragma unroll
        for (int off = 32; off >= 1; off >>= 1) {
            d0 += __shfl_xor(d0, off, 64);
            d1 += __shfl_xor(d1, off, 64);
        }
        int lane = tid & 63, wv = tid >> 6;
        if (lane == 0) { wpart[wv * 2] = d0; wpart[wv * 2 + 1] = d1; }
    }
    __syncthreads();
    if (tid < nrows)
        Drow[tid] = (wpart[tid] + wpart[2 + tid] + wpart[4 + tid] + wpart[6 + tid])
                    / (float)K;

    int Pb = prefix[CROWS];
    const float* W1 = swt;       const float* B1 = swt + 224;
    const float* W2 = swt + 256; const float* B2 = swt + 768;
    const float* W3 = swt + 784; float B3 = swt[800];

    // ---- Phase B: flat per-pair fused MLP (j from precomputed clist) ----
    for (int pp = tid; pp < Pb; pp += CTN) {
        int row = (pp >= prefix[1]) ? 1 : 0;
        int j = (int)p.clist[rowc[row] + (pp - prefix[row])];
        float4 bi = p.sel_box[r0 + row];
        float4 bj = p.sel_box[j];
        float ai = bi.z * bi.w, x2i = bi.x + bi.z, y2i = bi.y + bi.w;
        float iou = iou_of(bi.x, bi.y, ai, x2i, y2i, bj);
        float f1 = fabsf(bi.x - bj.x), f2 = fabsf(bi.y - bj.y);
        float f3 = fabsf(bi.z - bj.z), f4 = fabsf(bi.w - bj.w);
        float f5 = p.sel_score[r0 + row], f6 = p.sel_score[j];
        float acc2[16];
        #pragma unroll
        for (int q = 0; q < 16; q++) acc2[q] = B2[q];
        #pragma unroll 2
        for (int o = 0; o < 32; o++) {
            float a = B1[o];
            a += iou * W1[0 * 32 + o];
            a += f1 * W1[1 * 32 + o];
            a += f2 * W1[2 * 32 + o];
            a += f3 * W1[3 * 32 + o];
            a += f4 * W1[4 * 32 + o];
            a += f5 * W1[5 * 32 + o];
            a += f6 * W1[6 * 32 + o];
            float h = fmaxf(a, 0.0f);
            #pragma unroll
            for (int q = 0; q < 16; q++) acc2[q] += h * W2[o * 16 + q];
        }
        float acc3 = B3;
        #pragma unroll
        for (int q = 0; q < 16; q++) acc3 += fmaxf(acc2[q], 0.0f) * W3[q];
        atomicAdd(&Ssum[row], iou / (1.0f + expf(-acc3)));
    }
    __syncthreads();

    // ---- finale: lambda MLP + outputs for this block's rows ----
    if (tid < nrows) {
        int r = r0 + tid;
        float4 bi = p.sel_box[r];
        float si = p.sel_score[r];
        const float* LW1 = swt + 801; const float* LB1 = swt + 881;
        const float* LW2 = swt + 897; float LB2 = swt[913];
        float in5[5] = { bi.x, bi.y, bi.z, bi.w, si };
        float acc = LB2;
        #pragma unroll
        for (int o = 0; o < 16; o++) {
            float a2 = LB1[o];
            #pragma unroll
            for (int f = 0; f < 5; f++) a2 += in5[f] * LW1[f * 16 + o];
            acc += fmaxf(a2, 0.0f) * LW2[o];
        }
        float lam = 1.0f / (1.0f + expf(-acc));
        ((float4*)p.out_boxes)[r] = bi;
        p.out_cls[r] = (float)p.sel_cls[r];
        p.out_scores[r] = si * expf(-lam * Ssum[tid] * Drow[tid]);
    }
}

extern "C" void kernel_launch(void* const* d_in, const int* in_sizes, int n_in,
                              void* d_out, int out_size, void* d_ws, size_t ws_size,
                              hipStream_t stream) {
    int M = in_sizes[1];
    int K = (M < TOPK) ? M : TOPK;

    char* ws = (char*)d_ws;
    float4* sel_box   = (float4*)ws;           ws += (size_t)TOPK * 16;
    float*  sel_score = (float*)ws;            ws += (size_t)TOPK * 4;
    int*    sel_cls   = (int*)ws;              ws += (size_t)TOPK * 4;
    int*    cstart    = (int*)ws;              ws += (size_t)(NCLS + 2) * 4;
    short*  clist     = (short*)ws;            ws += (size_t)TOPK * 2;

    SelP sp;
    sp.scores  = (const float*)d_in[1];
    sp.boxes   = (const float*)d_in[0];
    sp.classes = (const int*)d_in[2];
    sp.M = M; sp.K = K;
    sp.sel_box = sel_box; sp.sel_score = sel_score; sp.sel_cls = sel_cls;

    PreP pp;
    pp.sel_cls = sel_cls; pp.K = K;
    pp.cstart = cstart; pp.clist = clist;

    CmpP cp;
    cp.sel_box = sel_box; cp.sel_score = sel_score; cp.sel_cls = sel_cls;
    cp.cstart = cstart; cp.clist = clist;
    cp.sw1 = (const float*)d_in[3];  cp.sb1 = (const float*)d_in[4];
    cp.sw2 = (const float*)d_in[5];  cp.sb2 = (const float*)d_in[6];
    cp.sw3 = (const float*)d_in[7];  cp.sb3 = (const float*)d_in[8];
    cp.lw1 = (const float*)d_in[9];  cp.lb1 = (const float*)d_in[10];
    cp.lw2 = (const float*)d_in[11]; cp.lb2 = (const float*)d_in[12];
    cp.K = K;
    cp.out_boxes  = (float*)d_out;
    cp.out_scores = (float*)d_out + (size_t)K * 4;
    cp.out_cls    = (float*)d_out + (size_t)K * 5;

    k_sel<<<K1B, STN, 0, stream>>>(sp);
    k_prep<<<1, PTN, 0, stream>>>(pp);
    k_cmp<<<(K + CROWS - 1) / CROWS, CTN, 0, stream>>>(cp);
}